// Round 10
// baseline (119.996 us; speedup 1.0000x reference)
//
#include <hip/hip_runtime.h>

#define B_ 32
#define N_ 64
#define F_ 128
#define E_ 4032
#define H_ 4
#define D_ 64

typedef __bf16 bf16x8 __attribute__((ext_vector_type(8)));
typedef __bf16 bf16x4 __attribute__((ext_vector_type(4)));
typedef float  f32x4  __attribute__((ext_vector_type(4)));

#define MFMA(a, b, c) __builtin_amdgcn_mfma_f32_16x16x32_bf16(a, b, c, 0, 0, 0)

// ws layout (float offsets):
//  s_fwd @0 (8192)   s_bwd @8192 (8192)   cnt @16384 (64 ints: [0..31] batch, [32] prep)
//  wb    @24576 (128)
//  M1bf  @24704 (4096f = 8192 bf16)   [128][64]
//  Wv2bf @28800 (8192f = 16384 bf16)  [128][128]
//  Wv3bf @36992 (4096f = 8192 bf16)   [64][128]
//  u_src @61568 (262144f = 524288 bf16) [8192][64]
//  u_tgt @323712 (262144f)

static __device__ inline bf16x8 ld_cvt8(const float* __restrict__ p) {
    float4 w0 = *(const float4*)p, w1 = *(const float4*)(p + 4);
    bf16x8 b;
    b[0]=(__bf16)w0.x; b[1]=(__bf16)w0.y; b[2]=(__bf16)w0.z; b[3]=(__bf16)w0.w;
    b[4]=(__bf16)w1.x; b[5]=(__bf16)w1.y; b[6]=(__bf16)w1.z; b[7]=(__bf16)w1.w;
    return b;
}

// Single kernel, 512 blocks x 256 thr (2 blocks/CU -> fully co-resident).
// Stage 1 (proj): block bid = (tile = bid>>2, head = bid&3): P GEMM col-split
//   across 4 waves -> scores -> U GEMM (src/tgt x col-half). Blocks 0..31 also
//   do weight prep (M1 = Wv1@We2, wb, bf16 Wv2/Wv3).
// Barrier: per-batch 16-block group counter + global prep counter (AGENT-scope
//   release/acquire; counters zeroed by hipMemsetAsync each call). Group b's
//   producers are exactly blocks [16b,16b+16) == its consumers -> deadlock-free.
// Stage 2 (fused edge+alpha+MLP): block = (b = bid>>4, quad = bid&15), as R9.
__global__ __launch_bounds__(256, 2) void k_all(
    const float* __restrict__ v_self, const float* __restrict__ W_proj,
    const float* __restrict__ We1,
    const float* __restrict__ a_fwd, const float* __restrict__ a_bwd,
    const float* __restrict__ Wv1, const float* __restrict__ We2,
    const float* __restrict__ be2, const float* __restrict__ Wv2,
    const float* __restrict__ Wv3, const float* __restrict__ be1,
    const float* __restrict__ bv1, const float* __restrict__ bv2,
    const float* __restrict__ bv3,
    float* __restrict__ s_fwd, float* __restrict__ s_bwd,
    __bf16* __restrict__ u_src, __bf16* __restrict__ u_tgt,
    __bf16* __restrict__ M1bf, float* __restrict__ wb,
    __bf16* __restrict__ Wv2bf, __bf16* __restrict__ Wv3bf,
    int* __restrict__ cnt,
    float* __restrict__ v_out, float* __restrict__ out_alpha)
{
    const int t = threadIdx.x;
    const int bid = blockIdx.x;
    const int b = bid >> 4;                     // batch (both stages)

    // ================= stage 1: proj unit =================
    {
        const int tile = bid >> 2, w = bid & 3; // 128 node-tiles x 4 heads
        const int node0 = tile * 16;
        const int wsub = t >> 6;                // wave in block (0..3)
        const int l = t & 63, q = l >> 4, lr = l & 15;

        __shared__ __bf16 P_lds[16 * 72];
        __shared__ float  spart_f[4][16], spart_b[4][16];

        // P GEMM, col-split: wave owns cols [wsub*16,+16), full K=128
        f32x4 acc = {};
#pragma unroll
        for (int ks = 0; ks < 4; ++ks) {
            bf16x8 a = ld_cvt8(v_self + (size_t)(node0 + lr) * 128 + ks * 32 + q * 8);
            bf16x8 bb = ld_cvt8(W_proj + (size_t)(w * 64 + wsub * 16 + lr) * 128 + ks * 32 + q * 8);
            acc = MFMA(a, bb, acc);
        }
        {
            float af = a_fwd[w * 64 + wsub * 16 + lr];
            float ab = a_bwd[w * 64 + wsub * 16 + lr];
            float pf[4], pb[4];
#pragma unroll
            for (int r = 0; r < 4; ++r) { pf[r] = acc[r] * af; pb[r] = acc[r] * ab; }
#pragma unroll
            for (int m = 1; m < 16; m <<= 1)
#pragma unroll
                for (int r = 0; r < 4; ++r) { pf[r] += __shfl_xor(pf[r], m); pb[r] += __shfl_xor(pb[r], m); }
            if (lr == 0) {
#pragma unroll
                for (int r = 0; r < 4; ++r) {
                    spart_f[wsub][q * 4 + r] = pf[r];
                    spart_b[wsub][q * 4 + r] = pb[r];
                }
            }
#pragma unroll
            for (int r = 0; r < 4; ++r)
                P_lds[(q * 4 + r) * 72 + wsub * 16 + lr] = (__bf16)acc[r];
        }
        __syncthreads();

        if (t < 16) {
            float sf = spart_f[0][t] + spart_f[1][t] + spart_f[2][t] + spart_f[3][t];
            float sb = spart_b[0][t] + spart_b[1][t] + spart_b[2][t] + spart_b[3][t];
            sf = (sf >= 0.f ? sf : 0.2f * sf) * 0.002f;
            sb = (sb >= 0.f ? sb : 0.2f * sb) * 0.002f;
            s_fwd[(node0 + t) * 4 + w] = sf;
            s_bwd[(node0 + t) * 4 + w] = sb;
        }

        // U GEMM: wave = (mm = src/tgt) x (cp = col-half), K=64
        const int mm = wsub >> 1, cp = wsub & 1;
        f32x4 uacc[2] = {};
#pragma unroll
        for (int ks = 0; ks < 2; ++ks) {
            bf16x8 a = *(const bf16x8*)&P_lds[lr * 72 + ks * 32 + q * 8];
#pragma unroll
            for (int c = 0; c < 2; ++c) {
                int ct = cp * 2 + c;
                bf16x8 bb = ld_cvt8(We1 + (size_t)(ct * 16 + lr) * 128 + mm * 64 + ks * 32 + q * 8);
                uacc[c] = MFMA(a, bb, uacc[c]);
            }
        }
        __bf16* up = (mm == 0) ? u_src : u_tgt;
#pragma unroll
        for (int c = 0; c < 2; ++c)
#pragma unroll
            for (int r = 0; r < 4; ++r) {
                size_t row = (size_t)(node0 + q * 4 + r) * 4 + w;
                up[row * 64 + (cp * 2 + c) * 16 + lr] = (__bf16)uacc[c][r];
            }
    }

    // ---- prep (blocks 0..31), after proj unit ----
    if (bid < 32) {
        const int pid = bid * 256 + t;          // 0..8191
        const int f = pid >> 6, k = pid & 63;
        float acc = 0.f;
#pragma unroll 8
        for (int dd = 0; dd < 64; ++dd)
            acc += Wv1[f * 64 + dd] * We2[dd * 64 + k];
        M1bf[pid] = (__bf16)acc;
        float p = Wv1[f * 64 + k] * be2[k];
#pragma unroll
        for (int m = 1; m < 64; m <<= 1) p += __shfl_xor(p, m);
        if (k == 0) wb[f] = p;
        Wv2bf[pid]        = (__bf16)Wv2[pid];
        Wv2bf[pid + 8192] = (__bf16)Wv2[pid + 8192];
        Wv3bf[pid]        = (__bf16)Wv3[pid];
    }

    // ================= group barrier =================
    __syncthreads();
    if (t == 0) {
        __threadfence();
        __hip_atomic_fetch_add(&cnt[b], 1, __ATOMIC_RELEASE, __HIP_MEMORY_SCOPE_AGENT);
        if (bid < 32)
            __hip_atomic_fetch_add(&cnt[32], 1, __ATOMIC_RELEASE, __HIP_MEMORY_SCOPE_AGENT);
        while (__hip_atomic_load(&cnt[b], __ATOMIC_ACQUIRE, __HIP_MEMORY_SCOPE_AGENT) < 16 ||
               __hip_atomic_load(&cnt[32], __ATOMIC_ACQUIRE, __HIP_MEMORY_SCOPE_AGENT) < 32)
            __builtin_amdgcn_s_sleep(2);
        __threadfence();
    }
    __syncthreads();

    // ================= stage 2: fused edge + alpha + MLP =================
    const int h = t >> 6, d = t & 63;           // wave = head
    const int quad = bid & 15;
    const int j0 = quad * 4;

    __shared__ __bf16 us_l[64][4][64];  // 32 KB [i][h][d] == global row order
    __shared__ float  ut_l[4][4][64];
    __shared__ float  aij_l[4][64][4];
    __shared__ float  suma_l[16];
    __shared__ __bf16 g_l[16 * 72];
    __shared__ __bf16 X1[16 * 136];
    __shared__ __bf16 X2[16 * 136];

    {   // stage u_src[b] (16384 bf16), coalesced
        const __bf16* ub = u_src + (size_t)b * 16384;
        __bf16* dst = &us_l[0][0][0];
#pragma unroll
        for (int it = 0; it < 8; ++it) {
            int idx = it * 2048 + t * 8;
            *(bf16x8*)(dst + idx) = *(const bf16x8*)(ub + idx);
        }
    }
    {   // stage u_tgt quartet as fp32
        int idx = t * 4;
        bf16x4 v = *(const bf16x4*)(u_tgt + (size_t)(b * 64 + j0) * 256 + idx);
        int j = idx >> 8, col = idx & 255;
        f32x4 f;
#pragma unroll
        for (int z = 0; z < 4; ++z) f[z] = (float)v[z];
        *(f32x4*)&ut_l[j][col >> 6][col & 63] = f;
    }

    // phase A: aij (lane = sender i) + suma
    {
        const int i = d;
        float sfi = s_fwd[(b * 64 + i) * 4 + h];
        float areg[4];
#pragma unroll
        for (int jl = 0; jl < 4; ++jl) {
            float sbj = s_bwd[(b * 64 + j0 + jl) * 4 + h];
            float m = fmaxf(sfi, sbj);
            float eij = __expf(__expf(sfi - m));
            float eji = __expf(__expf(sbj - m));
            float aij = eij / (eij + eji);
            if (i == j0 + jl) aij = 0.f;
            areg[jl] = aij;
        }
        f32x4 a4 = {areg[0], areg[1], areg[2], areg[3]};
        *(f32x4*)&aij_l[h][i][0] = a4;
#pragma unroll
        for (int jl = 0; jl < 4; ++jl) {
            float sa = areg[jl];
#pragma unroll
            for (int m2 = 1; m2 < 64; m2 <<= 1) sa += __shfl_xor(sa, m2);
            if (i == 0) suma_l[jl * 4 + h] = sa;
        }
    }
    // sender-role alpha (senders = the quartet, coalesced writes)
    if (t < 252) {
        const int jj = t >> 2, h2 = t & 3;
#pragma unroll
        for (int s = 0; s < 4; ++s) {
            int i2 = j0 + s;
            int j2 = jj + (jj >= i2 ? 1 : 0);
            float sfi = s_fwd[(b * 64 + i2) * 4 + h2];
            float sbj = s_bwd[(b * 64 + j2) * 4 + h2];
            float m = fmaxf(sfi, sbj);
            float eij = __expf(__expf(sfi - m));
            float eji = __expf(__expf(sbj - m));
            out_alpha[((size_t)b * E_ + i2 * 63 + jj) * 4 + h2] = eij / (eij + eji);
        }
    }
    __syncthreads();

    // phase B: g[jl,h,d] = sum_i aij * relu(aij*(us-ut) + ut + be1)
    {
        const float be1d = be1[d];
        float utv[4], utb[4];
#pragma unroll
        for (int jl = 0; jl < 4; ++jl) { utv[jl] = ut_l[jl][h][d]; utb[jl] = utv[jl] + be1d; }
        float gacc[4] = {};
        const __bf16* usp = &us_l[0][h][d];
#pragma unroll 8
        for (int i = 0; i < 64; ++i) {
            float usv = (float)usp[i * 256];
            f32x4 a4 = *(const f32x4*)&aij_l[h][i][0];
#pragma unroll
            for (int jl = 0; jl < 4; ++jl) {
                float a = a4[jl];
                float hp = fmaf(a, usv - utv[jl], utb[jl]);
                gacc[jl] = fmaf(a, fmaxf(hp, 0.f), gacc[jl]);
            }
        }
#pragma unroll
        for (int jl = 0; jl < 4; ++jl)
            g_l[(jl * 4 + h) * 72 + d] = (__bf16)gacc[jl];
    }
    __syncthreads();

    // phase C: MLP on one 16-row tile (4 nodes x 4 heads); wave = col slice
    const int w = h;
    const int q = d >> 4, lr = d & 15;

    f32x4 acc1[2] = {};
#pragma unroll
    for (int ks = 0; ks < 2; ++ks) {
        bf16x8 a = *(const bf16x8*)&g_l[lr * 72 + ks * 32 + q * 8];
#pragma unroll
        for (int c = 0; c < 2; ++c) {
            int ct = w * 2 + c;
            bf16x8 bb = *(const bf16x8*)(M1bf + (size_t)(ct * 16 + lr) * 64 + ks * 32 + q * 8);
            acc1[c] = MFMA(a, bb, acc1[c]);
        }
    }
    float sml[4];
#pragma unroll
    for (int r = 0; r < 4; ++r) sml[r] = suma_l[q * 4 + r];
#pragma unroll
    for (int c = 0; c < 2; ++c) {
        int f = (w * 2 + c) * 16 + lr;
        float wbf = wb[f], b1 = bv1[f];
#pragma unroll
        for (int r = 0; r < 4; ++r) {
            float xv = acc1[c][r] + sml[r] * wbf + b1;
            X1[(q * 4 + r) * 136 + f] = (__bf16)fmaxf(xv, 0.f);
        }
    }
    __syncthreads();

    f32x4 acc2[2] = {};
#pragma unroll
    for (int ks = 0; ks < 4; ++ks) {
        bf16x8 a = *(const bf16x8*)&X1[lr * 136 + ks * 32 + q * 8];
#pragma unroll
        for (int c = 0; c < 2; ++c) {
            int ct = w * 2 + c;
            bf16x8 bb = *(const bf16x8*)(Wv2bf + (size_t)(ct * 16 + lr) * 128 + ks * 32 + q * 8);
            acc2[c] = MFMA(a, bb, acc2[c]);
        }
    }
#pragma unroll
    for (int c = 0; c < 2; ++c) {
        int f = (w * 2 + c) * 16 + lr;
        float b2 = bv2[f];
#pragma unroll
        for (int r = 0; r < 4; ++r) {
            float xv = acc2[c][r] + b2;
            X2[(q * 4 + r) * 136 + f] = (__bf16)fmaxf(xv, 0.f);
        }
    }
    __syncthreads();

    f32x4 acc3 = {};
#pragma unroll
    for (int ks = 0; ks < 4; ++ks) {
        bf16x8 a = *(const bf16x8*)&X2[lr * 136 + ks * 32 + q * 8];
        bf16x8 bb = *(const bf16x8*)(Wv3bf + (size_t)(w * 16 + lr) * 128 + ks * 32 + q * 8);
        acc3 = MFMA(a, bb, acc3);
    }
    {
        int dd = w * 16 + lr;
        float b3 = bv3[dd];
        size_t rows_base = (size_t)(b * 64 + j0) * 4;
#pragma unroll
        for (int r = 0; r < 4; ++r)
            v_out[(rows_base + q * 4 + r) * 64 + dd] = acc3[r] + b3;
    }
}

extern "C" void kernel_launch(void* const* d_in, const int* in_sizes, int n_in,
                              void* d_out, int out_size, void* d_ws, size_t ws_size,
                              hipStream_t stream) {
    (void)in_sizes; (void)n_in; (void)out_size; (void)ws_size;
    const float* v_self = (const float*)d_in[0];
    const float* W_proj = (const float*)d_in[3];
    const float* a_fwd  = (const float*)d_in[4];
    const float* a_bwd  = (const float*)d_in[5];
    const float* We1    = (const float*)d_in[6];
    const float* be1    = (const float*)d_in[7];
    const float* We2    = (const float*)d_in[8];
    const float* be2    = (const float*)d_in[9];
    const float* Wv1    = (const float*)d_in[10];
    const float* bv1    = (const float*)d_in[11];
    const float* Wv2    = (const float*)d_in[12];
    const float* bv2    = (const float*)d_in[13];
    const float* Wv3    = (const float*)d_in[14];
    const float* bv3    = (const float*)d_in[15];

    float* ws = (float*)d_ws;
    float*  s_fwd = ws;
    float*  s_bwd = ws + 8192;
    int*    cnt   = (int*)(ws + 16384);
    float*  wb    = ws + 24576;
    __bf16* M1bf  = (__bf16*)(ws + 24704);
    __bf16* Wv2bf = (__bf16*)(ws + 28800);
    __bf16* Wv3bf = (__bf16*)(ws + 36992);
    __bf16* u_src = (__bf16*)(ws + 61568);
    __bf16* u_tgt = (__bf16*)(ws + 323712);

    float* v_out = (float*)d_out;
    float* alpha = v_out + (size_t)B_ * N_ * H_ * D_;

    // zero the barrier counters every call (graph-capture-legal async memset)
    hipMemsetAsync(cnt, 0, 64 * sizeof(int), stream);
    hipLaunchKernelGGL(k_all, dim3(512), dim3(256), 0, stream,
                       v_self, W_proj, We1, a_fwd, a_bwd, Wv1, We2, be2, Wv2, Wv3,
                       be1, bv1, bv2, bv3,
                       s_fwd, s_bwd, u_src, u_tgt, M1bf, wb, Wv2bf, Wv3bf,
                       cnt, v_out, alpha);
}

// Round 12
// 29.788 us; speedup vs baseline: 4.0284x; 4.0284x over previous
//
#include <hip/hip_runtime.h>

#define B_ 32
#define N_ 64
#define F_ 128
#define E_ 4032
#define H_ 4
#define D_ 64

typedef __bf16 bf16x8 __attribute__((ext_vector_type(8)));
typedef __bf16 bf16x4 __attribute__((ext_vector_type(4)));
typedef float  f32x4  __attribute__((ext_vector_type(4)));
typedef float  f32x2  __attribute__((ext_vector_type(2)));

#define MFMA(a, b, c) __builtin_amdgcn_mfma_f32_16x16x32_bf16(a, b, c, 0, 0, 0)

// ws layout (float offsets):
//  s_fwd @0 (8192)   s_bwd @8192 (8192)
//  wb    @24576 (128)
//  M1bf  @24704 (4096f = 8192 bf16)   [128][64]
//  Wv2bf @28800 (8192f = 16384 bf16)  [128][128]
//  Wv3bf @36992 (4096f = 8192 bf16)   [64][128]
//  u_src @61568 (262144f = 524288 bf16) [8192][64]
//  u_tgt @323712 (262144f)

static __device__ inline bf16x8 ld_cvt8(const float* __restrict__ p) {
    float4 w0 = *(const float4*)p, w1 = *(const float4*)(p + 4);
    bf16x8 b;
    b[0]=(__bf16)w0.x; b[1]=(__bf16)w0.y; b[2]=(__bf16)w0.z; b[3]=(__bf16)w0.w;
    b[4]=(__bf16)w1.x; b[5]=(__bf16)w1.y; b[6]=(__bf16)w1.z; b[7]=(__bf16)w1.w;
    return b;
}

// K1: blocks 0..31 — prep: M1 = Wv1@We2, wb = Wv1@be2, bf16 Wv2/Wv3.
// Blocks 32..543 — one (16-node tile, head) unit per 256-thr block, 4 waves:
//   P GEMM col-split across waves (full K=128, no reduce), scores via LDS
//   partials, U GEMM wave = (src/tgt) x (col-half).
__global__ __launch_bounds__(256) void k_proj(
    const float* __restrict__ v_self, const float* __restrict__ W_proj,
    const float* __restrict__ We1,
    const float* __restrict__ a_fwd, const float* __restrict__ a_bwd,
    const float* __restrict__ Wv1, const float* __restrict__ We2,
    const float* __restrict__ be2, const float* __restrict__ Wv2,
    const float* __restrict__ Wv3,
    float* __restrict__ s_fwd, float* __restrict__ s_bwd,
    __bf16* __restrict__ u_src, __bf16* __restrict__ u_tgt,
    __bf16* __restrict__ M1bf, float* __restrict__ wb,
    __bf16* __restrict__ Wv2bf, __bf16* __restrict__ Wv3bf)
{
    const int t = threadIdx.x;
    const int blk = blockIdx.x;

    if (blk < 32) {                             // ---- prep role ----
        const int pid = blk * 256 + t;          // 0..8191
        const int f = pid >> 6, k = pid & 63;
        float acc = 0.f;
#pragma unroll 8
        for (int dd = 0; dd < 64; ++dd)
            acc += Wv1[f * 64 + dd] * We2[dd * 64 + k];
        M1bf[pid] = (__bf16)acc;
        float p = Wv1[f * 64 + k] * be2[k];
#pragma unroll
        for (int m = 1; m < 64; m <<= 1) p += __shfl_xor(p, m);
        if (k == 0) wb[f] = p;
        Wv2bf[pid]        = (__bf16)Wv2[pid];
        Wv2bf[pid + 8192] = (__bf16)Wv2[pid + 8192];
        Wv3bf[pid]        = (__bf16)Wv3[pid];
        return;
    }

    const int bid = blk - 32;                   // 0..511
    const int tile = bid >> 2, w = bid & 3;     // 128 node-tiles x 4 heads
    const int node0 = tile * 16;
    const int wsub = t >> 6;                    // wave in block (0..3)
    const int l = t & 63, q = l >> 4, lr = l & 15;

    __shared__ __bf16 P_lds[16 * 72];           // [node][k] bf16
    __shared__ float  spart_f[4][16], spart_b[4][16];

    // ---- P GEMM, col-split: this wave owns cols [wsub*16,+16), full K=128 ----
    f32x4 acc = {};
#pragma unroll
    for (int ks = 0; ks < 4; ++ks) {
        bf16x8 a = ld_cvt8(v_self + (size_t)(node0 + lr) * 128 + ks * 32 + q * 8);
        bf16x8 bb = ld_cvt8(W_proj + (size_t)(w * 64 + wsub * 16 + lr) * 128 + ks * 32 + q * 8);
        acc = MFMA(a, bb, acc);
    }

    // scores partial over this wave's 16 cols; P -> LDS bf16
    {
        float af = a_fwd[w * 64 + wsub * 16 + lr];
        float ab = a_bwd[w * 64 + wsub * 16 + lr];
        float pf[4], pb[4];
#pragma unroll
        for (int r = 0; r < 4; ++r) { pf[r] = acc[r] * af; pb[r] = acc[r] * ab; }
#pragma unroll
        for (int m = 1; m < 16; m <<= 1)
#pragma unroll
            for (int r = 0; r < 4; ++r) { pf[r] += __shfl_xor(pf[r], m); pb[r] += __shfl_xor(pb[r], m); }
        if (lr == 0) {
#pragma unroll
            for (int r = 0; r < 4; ++r) {
                spart_f[wsub][q * 4 + r] = pf[r];
                spart_b[wsub][q * 4 + r] = pb[r];
            }
        }
#pragma unroll
        for (int r = 0; r < 4; ++r)
            P_lds[(q * 4 + r) * 72 + wsub * 16 + lr] = (__bf16)acc[r];
    }
    __syncthreads();

    // finalize scores (16 threads)
    if (t < 16) {
        float sf = spart_f[0][t] + spart_f[1][t] + spart_f[2][t] + spart_f[3][t];
        float sb = spart_b[0][t] + spart_b[1][t] + spart_b[2][t] + spart_b[3][t];
        sf = (sf >= 0.f ? sf : 0.2f * sf) * 0.002f;
        sb = (sb >= 0.f ? sb : 0.2f * sb) * 0.002f;
        s_fwd[(node0 + t) * 4 + w] = sf;
        s_bwd[(node0 + t) * 4 + w] = sb;
    }

    // ---- U GEMM: wave = (mm = src/tgt) x (cp = col-half), K = 64 ----
    const int mm = wsub >> 1, cp = wsub & 1;
    f32x4 uacc[2] = {};
#pragma unroll
    for (int ks = 0; ks < 2; ++ks) {
        bf16x8 a = *(const bf16x8*)&P_lds[lr * 72 + ks * 32 + q * 8];
#pragma unroll
        for (int c = 0; c < 2; ++c) {
            int ct = cp * 2 + c;
            bf16x8 bb = ld_cvt8(We1 + (size_t)(ct * 16 + lr) * 128 + mm * 64 + ks * 32 + q * 8);
            uacc[c] = MFMA(a, bb, uacc[c]);
        }
    }
    __bf16* up = (mm == 0) ? u_src : u_tgt;
#pragma unroll
    for (int c = 0; c < 2; ++c)
#pragma unroll
        for (int r = 0; r < 4; ++r) {
            size_t row = (size_t)(node0 + q * 4 + r) * 4 + w;   // (node, head)
            up[row * 64 + (cp * 2 + c) * 16 + lr] = (__bf16)uacc[c][r];
        }
}

// K2 (fused edge + alpha + MLP): block = (b, PAIR of receivers) -> 1024 blocks
// = 4 blocks/CU = 16 waves/CU. ~15 KB LDS. Phase B reads u_src straight from
// L2 (coalesced per-i). Phase C: half-filled 16-row MFMA tile (rows 8..15
// zero); only rows 0..7 stored.
__global__ __launch_bounds__(256) void k_fused(
    const float* __restrict__ s_fwd, const float* __restrict__ s_bwd,
    const __bf16* __restrict__ u_src, const __bf16* __restrict__ u_tgt,
    const float* __restrict__ be1,
    const __bf16* __restrict__ M1bf, const float* __restrict__ wb,
    const float* __restrict__ bv1,
    const __bf16* __restrict__ Wv2bf, const float* __restrict__ bv2,
    const __bf16* __restrict__ Wv3bf, const float* __restrict__ bv3,
    float* __restrict__ v_out, float* __restrict__ out_alpha)
{
    const int t = threadIdx.x;
    const int h = t >> 6, d = t & 63;           // wave = head, lane = d (= i in phase A)
    const int b = blockIdx.x >> 5, pr = blockIdx.x & 31;
    const int j0 = pr * 2;

    __shared__ float  ut_l[2][4][64];   // [jl][h][d]
    __shared__ float  aij_l[4][64][2];  // [h][i][jl]
    __shared__ float  suma_l[16];       // [jl*4+h], 8..15 zero
    __shared__ __bf16 g_l[16 * 72];     // rows 8..15 zero
    __shared__ __bf16 X1[16 * 136];
    __shared__ __bf16 X2[16 * 136];

    // stage u_tgt pair (512 bf16) as fp32
    {
        int idx = t * 2;                        // 0..510, covers all 512 elems
        const __bf16* utp = u_tgt + (size_t)(b * 64 + j0) * 256 + idx;
        int jl = idx >> 8, col = idx & 255;
        ut_l[jl][col >> 6][col & 63]             = (float)utp[0];
        ut_l[jl][(col + 1) >> 6][(col + 1) & 63] = (float)utp[1];
    }
    // zero g_l rows 8..15 (in-bounds: indices 576..1151)
    for (int idx = t * 4; idx < 8 * 72; idx += 256 * 4) {
        bf16x4 z = {};
        *(bf16x4*)&g_l[8 * 72 + idx] = z;
    }
    if (t >= 8 && t < 16) suma_l[t] = 0.f;

    // phase A: aij (lane = sender i) + suma for the 2 receivers
    {
        const int i = d;
        float sfi = s_fwd[(b * 64 + i) * 4 + h];
        float areg[2];
#pragma unroll
        for (int jl = 0; jl < 2; ++jl) {
            float sbj = s_bwd[(b * 64 + j0 + jl) * 4 + h];
            float m = fmaxf(sfi, sbj);
            float eij = __expf(__expf(sfi - m));
            float eji = __expf(__expf(sbj - m));
            float aij = eij / (eij + eji);
            if (i == j0 + jl) aij = 0.f;
            areg[jl] = aij;
        }
        f32x2 a2 = {areg[0], areg[1]};
        *(f32x2*)&aij_l[h][i][0] = a2;
#pragma unroll
        for (int jl = 0; jl < 2; ++jl) {
            float sa = areg[jl];
#pragma unroll
            for (int m2 = 1; m2 < 64; m2 <<= 1) sa += __shfl_xor(sa, m2);
            if (i == 0) suma_l[jl * 4 + h] = sa;
        }
    }
    // sender-role alpha (senders = the pair, coalesced writes)
    if (t < 252) {
        const int jj = t >> 2, h2 = t & 3;
#pragma unroll
        for (int s = 0; s < 2; ++s) {
            int i2 = j0 + s;
            int j2 = jj + (jj >= i2 ? 1 : 0);
            float sfi = s_fwd[(b * 64 + i2) * 4 + h2];
            float sbj = s_bwd[(b * 64 + j2) * 4 + h2];
            float m = fmaxf(sfi, sbj);
            float eij = __expf(__expf(sfi - m));
            float eji = __expf(__expf(sbj - m));
            out_alpha[((size_t)b * E_ + i2 * 63 + jj) * 4 + h2] = eij / (eij + eji);
        }
    }
    __syncthreads();

    // phase B: g[jl,h,d] = sum_i aij * relu(aij*(us-ut) + ut + be1); us from L2
    {
        const float be1d = be1[d];
        float utv[2], utb[2];
#pragma unroll
        for (int jl = 0; jl < 2; ++jl) { utv[jl] = ut_l[jl][h][d]; utb[jl] = utv[jl] + be1d; }
        float gacc[2] = {};
        const __bf16* usp = u_src + ((size_t)(b * 64) * 4 + h) * 64 + d;
#pragma unroll 8
        for (int i = 0; i < 64; ++i) {
            float usv = (float)usp[i * 256];
            f32x2 a2 = *(const f32x2*)&aij_l[h][i][0];   // uniform addr broadcast
#pragma unroll
            for (int jl = 0; jl < 2; ++jl) {
                float a = a2[jl];
                float hp = fmaf(a, usv - utv[jl], utb[jl]);
                gacc[jl] = fmaf(a, fmaxf(hp, 0.f), gacc[jl]);
            }
        }
#pragma unroll
        for (int jl = 0; jl < 2; ++jl)
            g_l[(jl * 4 + h) * 72 + d] = (__bf16)gacc[jl];
    }
    __syncthreads();

    // phase C: MLP; 16-row tile, rows 0..7 live (2 nodes x 4 heads); wave = col slice
    const int w = h;
    const int q = d >> 4, lr = d & 15;

    // layer 1: K=64, out 128 cols
    f32x4 acc1[2] = {};
#pragma unroll
    for (int ks = 0; ks < 2; ++ks) {
        bf16x8 a = *(const bf16x8*)&g_l[lr * 72 + ks * 32 + q * 8];
#pragma unroll
        for (int c = 0; c < 2; ++c) {
            int ct = w * 2 + c;
            bf16x8 bb = *(const bf16x8*)(M1bf + (size_t)(ct * 16 + lr) * 64 + ks * 32 + q * 8);
            acc1[c] = MFMA(a, bb, acc1[c]);
        }
    }
    float sml[4];
#pragma unroll
    for (int r = 0; r < 4; ++r) sml[r] = suma_l[q * 4 + r];
#pragma unroll
    for (int c = 0; c < 2; ++c) {
        int f = (w * 2 + c) * 16 + lr;
        float wbf = wb[f], b1 = bv1[f];
#pragma unroll
        for (int r = 0; r < 4; ++r) {
            float xv = acc1[c][r] + sml[r] * wbf + b1;
            X1[(q * 4 + r) * 136 + f] = (__bf16)fmaxf(xv, 0.f);
        }
    }
    __syncthreads();

    // layer 2: K=128, out 128 cols
    f32x4 acc2[2] = {};
#pragma unroll
    for (int ks = 0; ks < 4; ++ks) {
        bf16x8 a = *(const bf16x8*)&X1[lr * 136 + ks * 32 + q * 8];
#pragma unroll
        for (int c = 0; c < 2; ++c) {
            int ct = w * 2 + c;
            bf16x8 bb = *(const bf16x8*)(Wv2bf + (size_t)(ct * 16 + lr) * 128 + ks * 32 + q * 8);
            acc2[c] = MFMA(a, bb, acc2[c]);
        }
    }
#pragma unroll
    for (int c = 0; c < 2; ++c) {
        int f = (w * 2 + c) * 16 + lr;
        float b2 = bv2[f];
#pragma unroll
        for (int r = 0; r < 4; ++r) {
            float xv = acc2[c][r] + b2;
            X2[(q * 4 + r) * 136 + f] = (__bf16)fmaxf(xv, 0.f);
        }
    }
    __syncthreads();

    // layer 3: K=128, out 64 cols; fp32 out (rows 0..7 only)
    f32x4 acc3 = {};
#pragma unroll
    for (int ks = 0; ks < 4; ++ks) {
        bf16x8 a = *(const bf16x8*)&X2[lr * 136 + ks * 32 + q * 8];
        bf16x8 bb = *(const bf16x8*)(Wv3bf + (size_t)(w * 16 + lr) * 128 + ks * 32 + q * 8);
        acc3 = MFMA(a, bb, acc3);
    }
    if (q < 2) {
        int dd = w * 16 + lr;
        float b3 = bv3[dd];
        size_t rows_base = (size_t)(b * 64 + j0) * 4;
#pragma unroll
        for (int r = 0; r < 4; ++r)
            v_out[(rows_base + q * 4 + r) * 64 + dd] = acc3[r] + b3;
    }
}

extern "C" void kernel_launch(void* const* d_in, const int* in_sizes, int n_in,
                              void* d_out, int out_size, void* d_ws, size_t ws_size,
                              hipStream_t stream) {
    (void)in_sizes; (void)n_in; (void)out_size; (void)ws_size;
    const float* v_self = (const float*)d_in[0];
    const float* W_proj = (const float*)d_in[3];
    const float* a_fwd  = (const float*)d_in[4];
    const float* a_bwd  = (const float*)d_in[5];
    const float* We1    = (const float*)d_in[6];
    const float* be1    = (const float*)d_in[7];
    const float* We2    = (const float*)d_in[8];
    const float* be2    = (const float*)d_in[9];
    const float* Wv1    = (const float*)d_in[10];
    const float* bv1    = (const float*)d_in[11];
    const float* Wv2    = (const float*)d_in[12];
    const float* bv2    = (const float*)d_in[13];
    const float* Wv3    = (const float*)d_in[14];
    const float* bv3    = (const float*)d_in[15];

    float* ws = (float*)d_ws;
    float*  s_fwd = ws;
    float*  s_bwd = ws + 8192;
    float*  wb    = ws + 24576;
    __bf16* M1bf  = (__bf16*)(ws + 24704);
    __bf16* Wv2bf = (__bf16*)(ws + 28800);
    __bf16* Wv3bf = (__bf16*)(ws + 36992);
    __bf16* u_src = (__bf16*)(ws + 61568);
    __bf16* u_tgt = (__bf16*)(ws + 323712);

    float* v_out = (float*)d_out;
    float* alpha = v_out + (size_t)B_ * N_ * H_ * D_;

    hipLaunchKernelGGL(k_proj, dim3(32 + 512), dim3(256), 0, stream,
                       v_self, W_proj, We1, a_fwd, a_bwd, Wv1, We2, be2, Wv2, Wv3,
                       s_fwd, s_bwd, u_src, u_tgt, M1bf, wb, Wv2bf, Wv3bf);
    hipLaunchKernelGGL(k_fused, dim3(B_ * N_ / 2), dim3(256), 0, stream,
                       s_fwd, s_bwd, u_src, u_tgt, be1, M1bf, wb, bv1,
                       Wv2bf, bv2, Wv3bf, bv3, v_out, alpha);
}

// Round 13
// 25.818 us; speedup vs baseline: 4.6478x; 1.1538x over previous
//
#include <hip/hip_runtime.h>

#define B_ 32
#define N_ 64
#define F_ 128
#define E_ 4032
#define H_ 4
#define D_ 64

typedef __bf16 bf16x8 __attribute__((ext_vector_type(8)));
typedef __bf16 bf16x4 __attribute__((ext_vector_type(4)));
typedef float  f32x4  __attribute__((ext_vector_type(4)));

#define MFMA(a, b, c) __builtin_amdgcn_mfma_f32_16x16x32_bf16(a, b, c, 0, 0, 0)

// ws layout (float offsets):
//  s_fwd @0 (8192)   s_bwd @8192 (8192)
//  wb    @24576 (128)
//  M1bf  @24704 (4096f = 8192 bf16)   [128][64]
//  Wv2bf @28800 (8192f = 16384 bf16)  [128][128]
//  Wv3bf @36992 (4096f = 8192 bf16)   [64][128]
//  u_src @61568 (262144f = 524288 bf16) [8192][64]
//  u_tgt @323712 (262144f)

static __device__ inline bf16x8 ld_cvt8(const float* __restrict__ p) {
    float4 w0 = *(const float4*)p, w1 = *(const float4*)(p + 4);
    bf16x8 b;
    b[0]=(__bf16)w0.x; b[1]=(__bf16)w0.y; b[2]=(__bf16)w0.z; b[3]=(__bf16)w0.w;
    b[4]=(__bf16)w1.x; b[5]=(__bf16)w1.y; b[6]=(__bf16)w1.z; b[7]=(__bf16)w1.w;
    return b;
}

// K1: blocks 0..31 — prep (first, so its tail never gates k_fused):
//   M1 = Wv1@We2, wb = Wv1@be2, bf16 Wv2/Wv3.
// Blocks 32..287 — two (16-node tile, head) units per 256-thr block. Unit =
//   2 waves: P(16x64,K=128) split K-halves across the wave pair (LDS fp32
//   reduce), then wave0 -> U_src, wave1 -> U_tgt (K=64 each).
__global__ __launch_bounds__(256) void k_proj(
    const float* __restrict__ v_self, const float* __restrict__ W_proj,
    const float* __restrict__ We1,
    const float* __restrict__ a_fwd, const float* __restrict__ a_bwd,
    const float* __restrict__ Wv1, const float* __restrict__ We2,
    const float* __restrict__ be2, const float* __restrict__ Wv2,
    const float* __restrict__ Wv3,
    float* __restrict__ s_fwd, float* __restrict__ s_bwd,
    __bf16* __restrict__ u_src, __bf16* __restrict__ u_tgt,
    __bf16* __restrict__ M1bf, float* __restrict__ wb,
    __bf16* __restrict__ Wv2bf, __bf16* __restrict__ Wv3bf)
{
    const int t = threadIdx.x;
    const int blk = blockIdx.x;

    if (blk < 32) {                             // ---- prep role ----
        const int pid = blk * 256 + t;          // 0..8191
        const int f = pid >> 6, k = pid & 63;
        float acc = 0.f;
#pragma unroll 8
        for (int dd = 0; dd < 64; ++dd)
            acc += Wv1[f * 64 + dd] * We2[dd * 64 + k];
        M1bf[pid] = (__bf16)acc;
        float p = Wv1[f * 64 + k] * be2[k];
#pragma unroll
        for (int m = 1; m < 64; m <<= 1) p += __shfl_xor(p, m);
        if (k == 0) wb[f] = p;
        Wv2bf[pid]        = (__bf16)Wv2[pid];
        Wv2bf[pid + 8192] = (__bf16)Wv2[pid + 8192];
        Wv3bf[pid]        = (__bf16)Wv3[pid];
        return;
    }

    const int u = t >> 7;                       // unit within block (0,1)
    const int wsub = (t >> 6) & 1;              // wave within unit
    const int l = t & 63, q = l >> 4, lr = l & 15;
    const int gu = (blk - 32) * 2 + u;          // 0..511
    const int tile = gu >> 2, w = gu & 3;       // 128 node-tiles x 4 heads
    const int node0 = tile * 16;

    __shared__ float  accp[2][16][68];          // K-half partials (fp32)
    __shared__ __bf16 P_lds[2][16 * 72];

    // P GEMM: this wave does K-chunks {2*wsub, 2*wsub+1} (K=64 of 128)
    f32x4 acc[4] = {};
#pragma unroll
    for (int kk = 0; kk < 2; ++kk) {
        int ks = wsub * 2 + kk;
        bf16x8 a = ld_cvt8(v_self + (size_t)(node0 + lr) * 128 + ks * 32 + q * 8);
#pragma unroll
        for (int ct = 0; ct < 4; ++ct) {
            bf16x8 bb = ld_cvt8(W_proj + (size_t)(w * 64 + ct * 16 + lr) * 128 + ks * 32 + q * 8);
            acc[ct] = MFMA(a, bb, acc[ct]);
        }
    }
    if (wsub == 1) {
#pragma unroll
        for (int ct = 0; ct < 4; ++ct)
#pragma unroll
            for (int r = 0; r < 4; ++r)
                accp[u][q * 4 + r][ct * 16 + lr] = acc[ct][r];
    }
    __syncthreads();

    if (wsub == 0) {
        // reduce K-halves; scores; P -> LDS bf16
        float pf[4] = {0,0,0,0}, pb[4] = {0,0,0,0};
#pragma unroll
        for (int ct = 0; ct < 4; ++ct) {
            float af = a_fwd[w * 64 + ct * 16 + lr];
            float ab = a_bwd[w * 64 + ct * 16 + lr];
#pragma unroll
            for (int r = 0; r < 4; ++r) {
                float full = acc[ct][r] + accp[u][q * 4 + r][ct * 16 + lr];
                acc[ct][r] = full;
                pf[r] += full * af;
                pb[r] += full * ab;
            }
        }
#pragma unroll
        for (int m = 1; m < 16; m <<= 1) {
#pragma unroll
            for (int r = 0; r < 4; ++r) { pf[r] += __shfl_xor(pf[r], m); pb[r] += __shfl_xor(pb[r], m); }
        }
        if (lr == 0) {
#pragma unroll
            for (int r = 0; r < 4; ++r) {
                float x = pf[r]; x = (x >= 0.f ? x : 0.2f * x) * 0.002f;
                float y = pb[r]; y = (y >= 0.f ? y : 0.2f * y) * 0.002f;
                s_fwd[(node0 + q * 4 + r) * 4 + w] = x;
                s_bwd[(node0 + q * 4 + r) * 4 + w] = y;
            }
        }
#pragma unroll
        for (int ct = 0; ct < 4; ++ct)
#pragma unroll
            for (int r = 0; r < 4; ++r)
                P_lds[u][(q * 4 + r) * 72 + ct * 16 + lr] = (__bf16)acc[ct][r];
    }
    __syncthreads();

    // U GEMM: wave wsub does (0 -> u_src, 1 -> u_tgt), K = 64
    const int mm = wsub;
    f32x4 uacc[4] = {};
#pragma unroll
    for (int ks = 0; ks < 2; ++ks) {
        bf16x8 a = *(const bf16x8*)&P_lds[u][lr * 72 + ks * 32 + q * 8];
#pragma unroll
        for (int ct = 0; ct < 4; ++ct) {
            bf16x8 bb = ld_cvt8(We1 + (size_t)(ct * 16 + lr) * 128 + mm * 64 + ks * 32 + q * 8);
            uacc[ct] = MFMA(a, bb, uacc[ct]);
        }
    }
    __bf16* up = (mm == 0) ? u_src : u_tgt;
#pragma unroll
    for (int ct = 0; ct < 4; ++ct)
#pragma unroll
        for (int r = 0; r < 4; ++r) {
            size_t row = (size_t)(node0 + q * 4 + r) * 4 + w;   // (node, head)
            up[row * 64 + ct * 16 + lr] = (__bf16)uacc[ct][r];
        }
}

// K2 (fused edge + alpha + MLP): block = (b, quartet of 4 receivers), 512 blocks.
// Phase B reads u_src from L2 (unroll-8). Phase C: one full 16-row MFMA tile
// (4 nodes x 4 heads). ~19 KB LDS -> 2 blocks/CU.
__global__ __launch_bounds__(256) void k_fused(
    const float* __restrict__ s_fwd, const float* __restrict__ s_bwd,
    const __bf16* __restrict__ u_src, const __bf16* __restrict__ u_tgt,
    const float* __restrict__ be1,
    const __bf16* __restrict__ M1bf, const float* __restrict__ wb,
    const float* __restrict__ bv1,
    const __bf16* __restrict__ Wv2bf, const float* __restrict__ bv2,
    const __bf16* __restrict__ Wv3bf, const float* __restrict__ bv3,
    float* __restrict__ v_out, float* __restrict__ out_alpha)
{
    const int t = threadIdx.x;
    const int h = t >> 6, d = t & 63;           // wave = head, lane = d (= i in phase A)
    const int b = blockIdx.x >> 4, quad = blockIdx.x & 15;
    const int j0 = quad * 4;

    __shared__ float  ut_l[4][4][64];   // [jl][h][d]
    __shared__ float  aij_l[4][64][4];  // [h][i][jl]
    __shared__ float  suma_l[16];       // [jl*4+h]
    __shared__ __bf16 g_l[16 * 72];
    __shared__ __bf16 X1[16 * 136];
    __shared__ __bf16 X2[16 * 136];

    // stage u_tgt for the quartet (1024 bf16)
    {
        int idx = t * 4;
        bf16x4 v = *(const bf16x4*)(u_tgt + (size_t)(b * 64 + j0) * 256 + idx);
        int j = idx >> 8, col = idx & 255;
        f32x4 f;
#pragma unroll
        for (int z = 0; z < 4; ++z) f[z] = (float)v[z];
        *(f32x4*)&ut_l[j][col >> 6][col & 63] = f;
    }

    // phase A: aij (lane = sender i) + suma
    {
        const int i = d;
        float sfi = s_fwd[(b * 64 + i) * 4 + h];
        float areg[4];
#pragma unroll
        for (int jl = 0; jl < 4; ++jl) {
            float sbj = s_bwd[(b * 64 + j0 + jl) * 4 + h];
            float m = fmaxf(sfi, sbj);
            float eij = __expf(__expf(sfi - m));
            float eji = __expf(__expf(sbj - m));
            float aij = eij / (eij + eji);
            if (i == j0 + jl) aij = 0.f;
            areg[jl] = aij;
        }
        f32x4 a4 = {areg[0], areg[1], areg[2], areg[3]};
        *(f32x4*)&aij_l[h][i][0] = a4;
#pragma unroll
        for (int jl = 0; jl < 4; ++jl) {
            float sa = areg[jl];
#pragma unroll
            for (int m2 = 1; m2 < 64; m2 <<= 1) sa += __shfl_xor(sa, m2);
            if (i == 0) suma_l[jl * 4 + h] = sa;
        }
    }
    // sender-role alpha (senders = the quartet, coalesced writes)
    if (t < 252) {
        const int jj = t >> 2, h2 = t & 3;
#pragma unroll
        for (int s = 0; s < 4; ++s) {
            int i2 = j0 + s;
            int j2 = jj + (jj >= i2 ? 1 : 0);
            float sfi = s_fwd[(b * 64 + i2) * 4 + h2];
            float sbj = s_bwd[(b * 64 + j2) * 4 + h2];
            float m = fmaxf(sfi, sbj);
            float eij = __expf(__expf(sfi - m));
            float eji = __expf(__expf(sbj - m));
            out_alpha[((size_t)b * E_ + i2 * 63 + jj) * 4 + h2] = eij / (eij + eji);
        }
    }
    __syncthreads();

    // phase B: g[jl,h,d] = sum_i aij * relu(aij*(us-ut) + ut + be1); u_src from L2
    {
        const float be1d = be1[d];
        float utv[4], utb[4];
#pragma unroll
        for (int jl = 0; jl < 4; ++jl) { utv[jl] = ut_l[jl][h][d]; utb[jl] = utv[jl] + be1d; }
        float gacc[4] = {};
        const __bf16* usp = u_src + ((size_t)(b * 64) * 4 + h) * 64 + d;
#pragma unroll 8
        for (int i = 0; i < 64; ++i) {
            float usv = (float)usp[i * 256];
            f32x4 a4 = *(const f32x4*)&aij_l[h][i][0];   // uniform addr -> broadcast
#pragma unroll
            for (int jl = 0; jl < 4; ++jl) {
                float a = a4[jl];
                float hp = fmaf(a, usv - utv[jl], utb[jl]);
                gacc[jl] = fmaf(a, fmaxf(hp, 0.f), gacc[jl]);
            }
        }
#pragma unroll
        for (int jl = 0; jl < 4; ++jl)
            g_l[(jl * 4 + h) * 72 + d] = (__bf16)gacc[jl];
    }
    __syncthreads();

    // phase C: MLP on one 16-row tile; wave w covers its column slice
    const int w = h;
    const int q = d >> 4, lr = d & 15;

    // layer 1: K=64, out 128 cols
    f32x4 acc1[2] = {};
#pragma unroll
    for (int ks = 0; ks < 2; ++ks) {
        bf16x8 a = *(const bf16x8*)&g_l[lr * 72 + ks * 32 + q * 8];
#pragma unroll
        for (int c = 0; c < 2; ++c) {
            int ct = w * 2 + c;
            bf16x8 bb = *(const bf16x8*)(M1bf + (size_t)(ct * 16 + lr) * 64 + ks * 32 + q * 8);
            acc1[c] = MFMA(a, bb, acc1[c]);
        }
    }
    float sml[4];
#pragma unroll
    for (int r = 0; r < 4; ++r) sml[r] = suma_l[q * 4 + r];
#pragma unroll
    for (int c = 0; c < 2; ++c) {
        int f = (w * 2 + c) * 16 + lr;
        float wbf = wb[f], b1 = bv1[f];
#pragma unroll
        for (int r = 0; r < 4; ++r) {
            float xv = acc1[c][r] + sml[r] * wbf + b1;
            X1[(q * 4 + r) * 136 + f] = (__bf16)fmaxf(xv, 0.f);
        }
    }
    __syncthreads();

    // layer 2: K=128, out 128 cols
    f32x4 acc2[2] = {};
#pragma unroll
    for (int ks = 0; ks < 4; ++ks) {
        bf16x8 a = *(const bf16x8*)&X1[lr * 136 + ks * 32 + q * 8];
#pragma unroll
        for (int c = 0; c < 2; ++c) {
            int ct = w * 2 + c;
            bf16x8 bb = *(const bf16x8*)(Wv2bf + (size_t)(ct * 16 + lr) * 128 + ks * 32 + q * 8);
            acc2[c] = MFMA(a, bb, acc2[c]);
        }
    }
#pragma unroll
    for (int c = 0; c < 2; ++c) {
        int f = (w * 2 + c) * 16 + lr;
        float b2 = bv2[f];
#pragma unroll
        for (int r = 0; r < 4; ++r) {
            float xv = acc2[c][r] + b2;
            X2[(q * 4 + r) * 136 + f] = (__bf16)fmaxf(xv, 0.f);
        }
    }
    __syncthreads();

    // layer 3: K=128, out 64 cols; fp32 out
    f32x4 acc3 = {};
#pragma unroll
    for (int ks = 0; ks < 4; ++ks) {
        bf16x8 a = *(const bf16x8*)&X2[lr * 136 + ks * 32 + q * 8];
        bf16x8 bb = *(const bf16x8*)(Wv3bf + (size_t)(w * 16 + lr) * 128 + ks * 32 + q * 8);
        acc3 = MFMA(a, bb, acc3);
    }
    {
        int dd = w * 16 + lr;
        float b3 = bv3[dd];
        size_t rows_base = (size_t)(b * 64 + j0) * 4;
#pragma unroll
        for (int r = 0; r < 4; ++r)
            v_out[(rows_base + q * 4 + r) * 64 + dd] = acc3[r] + b3;
    }
}

extern "C" void kernel_launch(void* const* d_in, const int* in_sizes, int n_in,
                              void* d_out, int out_size, void* d_ws, size_t ws_size,
                              hipStream_t stream) {
    (void)in_sizes; (void)n_in; (void)out_size; (void)ws_size;
    const float* v_self = (const float*)d_in[0];
    const float* W_proj = (const float*)d_in[3];
    const float* a_fwd  = (const float*)d_in[4];
    const float* a_bwd  = (const float*)d_in[5];
    const float* We1    = (const float*)d_in[6];
    const float* be1    = (const float*)d_in[7];
    const float* We2    = (const float*)d_in[8];
    const float* be2    = (const float*)d_in[9];
    const float* Wv1    = (const float*)d_in[10];
    const float* bv1    = (const float*)d_in[11];
    const float* Wv2    = (const float*)d_in[12];
    const float* bv2    = (const float*)d_in[13];
    const float* Wv3    = (const float*)d_in[14];
    const float* bv3    = (const float*)d_in[15];

    float* ws = (float*)d_ws;
    float*  s_fwd = ws;
    float*  s_bwd = ws + 8192;
    float*  wb    = ws + 24576;
    __bf16* M1bf  = (__bf16*)(ws + 24704);
    __bf16* Wv2bf = (__bf16*)(ws + 28800);
    __bf16* Wv3bf = (__bf16*)(ws + 36992);
    __bf16* u_src = (__bf16*)(ws + 61568);
    __bf16* u_tgt = (__bf16*)(ws + 323712);

    float* v_out = (float*)d_out;
    float* alpha = v_out + (size_t)B_ * N_ * H_ * D_;

    hipLaunchKernelGGL(k_proj, dim3(32 + 256), dim3(256), 0, stream,
                       v_self, W_proj, We1, a_fwd, a_bwd, Wv1, We2, be2, Wv2, Wv3,
                       s_fwd, s_bwd, u_src, u_tgt, M1bf, wb, Wv2bf, Wv3bf);
    hipLaunchKernelGGL(k_fused, dim3(B_ * N_ / 4), dim3(256), 0, stream,
                       s_fwd, s_bwd, u_src, u_tgt, be1, M1bf, wb, bv1,
                       Wv2bf, bv2, Wv3bf, bv3, v_out, alpha);
}